// Round 12
// baseline (254.111 us; speedup 1.0000x reference)
//
#include <hip/hip_runtime.h>
#include <math.h>

#define B 16
#define K 128
#define S 64
#define L 2
#define D 256
#define A 500

#define ROW4_TREES 4096            // 16384 floats / 4 (64 KB)
#define HALF4_HID  4160            // half of a 130 KB hiddens/cells row

// Sentinel for masked beams: far below any N(0,1) score, and FINITE after a
// bf16 round-trip (-FLT_MAX rounds to bf16 -inf -> NaN in harness absmax).
#define NEG_BIG (-1.0e30f)

typedef float f32x4 __attribute__((ext_vector_type(4)));
typedef int   i32x4 __attribute__((ext_vector_type(4)));

// d_out float offsets (concatenated return tuple, all float32)
#define OFF_GENLL 0
#define OFF_TREES 2048
#define OFF_HID   33556480
#define OFF_CELLS 101713920
#define OFF_MARG  169871360
#define OFF_ACT   169871376
#define OFF_APOS  170895376
#define OFF_PTR   170897424
#define OFF_PREV  170899472
#define OFF_NBW   170901520

// SCATTER form: block (b,k) reads source row (b,k) contiguously (loads issue
// at cycle 0) and writes to output row rank(k). rank(k) needs only a
// rank-of-ONE: one compare/thread vs broadcast key_k + block reduce (~100cy),
// not a full 128-iter sort (~800cy). Only the 16 k==0 trees blocks compute
// the full permutation (for the small outputs).
#define NU_TREES 2048
#define GRID (NU_TREES + 8192)     // 10240 blocks, one 64KB unit each

__global__ void __launch_bounds__(256, 8)
k_fused(const float* __restrict__ gen_ll,
        const f32x4* __restrict__ trees,
        const f32x4* __restrict__ hiddens,
        const f32x4* __restrict__ cells,
        const int* __restrict__ actions,
        const int* __restrict__ actions_pos,
        const int* __restrict__ pointer,
        const int* __restrict__ beam_widths,
        float* __restrict__ out)
{
    __shared__ float key[K];
    __shared__ int   sidx[K];
    __shared__ int   redi[4];
    __shared__ float red[4];

    const int tid = threadIdx.x;
    const int bid = blockIdx.x;

    // decode SOURCE work item
    int b, k, which = -1, half = 0;
    if (bid < NU_TREES) {
        b = bid >> 7; k = bid & 127;
    } else {
        const int u2 = bid - NU_TREES;            // [0, 8192)
        which = u2 >> 12;                          // 0 = hiddens, 1 = cells
        const int u3 = u2 & 4095;                  // 2*row + half
        half = u3 & 1;
        const int row = u3 >> 1;
        b = row >> 7; k = row & 127;
    }

    // source pointer is sort-independent: issue first 8-deep load batch NOW
    const f32x4* s = (which < 0)
        ? trees + (size_t)(b * K + k) * ROW4_TREES
        : (which ? cells : hiddens) + ((size_t)(b * K + k) * 2 + half) * HALF4_HID;
    f32x4 v[8];
#pragma unroll
    for (int i = 0; i < 8; ++i)
        v[i] = __builtin_nontemporal_load(&s[i * 256 + tid]);

    // --- rank-of-one: destination row = #(key_i > key_k) + stable tie-break ---
    const int w = beam_widths[b];
    const float gk = gen_ll[b * K + k];            // block-uniform scalar load
    const float keyk = (k < w) ? gk : NEG_BIG;
    int c = 0;
    if (tid < K) {
        const float keyt = (tid < w) ? gen_ll[b * K + tid] : NEG_BIG;
        c = (keyt > keyk) || (keyt == keyk && tid < k);
    }
#pragma unroll
    for (int mask = 32; mask >= 1; mask >>= 1)
        c += __shfl_xor(c, mask, 64);
    if ((tid & 63) == 0) redi[tid >> 6] = c;
    __syncthreads();
    const int rr = redi[0] + redi[1] + redi[2] + redi[3];  // waves 2,3 add 0

    if (which < 0) {
        f32x4* d = (f32x4*)(out + OFF_TREES) + (size_t)((b << 7) + rr) * ROW4_TREES;
#pragma unroll
        for (int i = 0; i < 8; ++i)
            __builtin_nontemporal_store(v[i], &d[i * 256 + tid]);
#pragma unroll
        for (int i = 0; i < 8; ++i)
            v[i] = __builtin_nontemporal_load(&s[(8 + i) * 256 + tid]);
#pragma unroll
        for (int i = 0; i < 8; ++i)
            __builtin_nontemporal_store(v[i], &d[(8 + i) * 256 + tid]);

        // piggyback: actions row (b,k) -> rank row. 500 ints = 125 int4.
        {
            const i32x4* sa = (const i32x4*)actions + (size_t)(b * K + k) * 125;
            f32x4* da = (f32x4*)(out + OFF_ACT) + (size_t)((b << 7) + rr) * 125;
            if (tid < 125) {
                const i32x4 av = __builtin_nontemporal_load(&sa[tid]);
                f32x4 f;
                f.x = (float)av.x; f.y = (float)av.y; f.z = (float)av.z; f.w = (float)av.w;
                __builtin_nontemporal_store(f, &da[tid]);
            }
        }

        // full sort + small outputs: only the 16 blocks with k==0 (bid = b*128)
        if (k == 0) {
            if (tid < K) key[tid] = (tid < w) ? gen_ll[b * K + tid] : NEG_BIG;
            __syncthreads();
            if (tid < K) {
                const float my = key[tid];
                int rank = 0;
#pragma unroll 16
                for (int i = 0; i < K; ++i) {
                    const float ki = key[i];       // wave-broadcast LDS read
                    rank += (ki > my) || (ki == my && i < tid);
                }
                sidx[rank] = tid;                  // stable permutation
            }
            __syncthreads();
            if (tid < K) {
                const int jj = sidx[tid];
                out[OFF_GENLL + b * K + tid] = key[jj];
                const int ap = actions_pos[b * K + jj];
                out[OFF_APOS + b * K + tid] = (float)ap;
                out[OFF_PTR  + b * K + tid] = (float)pointer[b * K + jj];
                out[OFF_PREV + b * K + tid] = (float)actions[(size_t)(b * K + jj) * A + ap];
            }
            const float vv = (tid < K) ? key[tid] : NEG_BIG;
            if (tid < 128) {
                float m = vv;
#pragma unroll
                for (int mask = 32; mask >= 1; mask >>= 1)
                    m = fmaxf(m, __shfl_xor(m, mask, 64));
                if ((tid & 63) == 0) red[tid >> 6] = m;
            }
            __syncthreads();
            const float m = fmaxf(red[0], red[1]);
            if (tid < 128) {
                float e = expf(vv - m);            // masked lanes -> exactly 0
#pragma unroll
                for (int mask = 32; mask >= 1; mask >>= 1)
                    e += __shfl_xor(e, mask, 64);
                if ((tid & 63) == 0) red[2 + (tid >> 6)] = e;
            }
            __syncthreads();
            if (tid == 0) {
                out[OFF_MARG + b] = m + logf(red[2] + red[3]);
                out[OFF_NBW + b] = (float)(w < K ? w : K);
            }
        }
    } else {
        f32x4* d = (f32x4*)(out + (which ? OFF_CELLS : OFF_HID))
                 + ((size_t)((b << 7) + rr) * 2 + half) * HALF4_HID;
#pragma unroll
        for (int i = 0; i < 8; ++i)
            __builtin_nontemporal_store(v[i], &d[i * 256 + tid]);
#pragma unroll
        for (int i = 0; i < 8; ++i)
            v[i] = __builtin_nontemporal_load(&s[(8 + i) * 256 + tid]);
#pragma unroll
        for (int i = 0; i < 8; ++i)
            __builtin_nontemporal_store(v[i], &d[(8 + i) * 256 + tid]);
        // remainder: 4160 = 16*256 + 64
        if (tid < 64) {
            const f32x4 t = __builtin_nontemporal_load(&s[16 * 256 + tid]);
            __builtin_nontemporal_store(t, &d[16 * 256 + tid]);
        }
    }
}

extern "C" void kernel_launch(void* const* d_in, const int* in_sizes, int n_in,
                              void* d_out, int out_size, void* d_ws, size_t ws_size,
                              hipStream_t stream)
{
    const float* gen_ll      = (const float*)d_in[0];
    const float* trees       = (const float*)d_in[1];
    const float* hiddens     = (const float*)d_in[2];
    const float* cells       = (const float*)d_in[3];
    const int*   actions     = (const int*)d_in[4];
    const int*   actions_pos = (const int*)d_in[5];
    const int*   pointer     = (const int*)d_in[6];
    const int*   beam_widths = (const int*)d_in[7];
    float* out = (float*)d_out;

    k_fused<<<GRID, 256, 0, stream>>>(gen_ll, (const f32x4*)trees,
                                      (const f32x4*)hiddens, (const f32x4*)cells,
                                      actions, actions_pos, pointer, beam_widths, out);
}